// Round 12
// baseline (258.525 us; speedup 1.0000x reference)
//
#include <hip/hip_runtime.h>
#include <hip/hip_bf16.h>

#define NFACE 400000
#define NVERT 200000
#define CIN 64
#define COUT 128
#define KF 27
#define BN_EPS 1e-5f
#define LST 56            // Af row stride (shorts): 112B, bank-spread
#define BST 40            // Bs/swb row stride (shorts): 80B, bank-spread
#define NCPY 8            // XCD-local adjacency copies
#define OVF_CAP 4096

typedef __attribute__((ext_vector_type(8))) short bf16x8;
typedef __attribute__((ext_vector_type(4))) float f32x4;

__device__ __forceinline__ short f2bf(float x) {
    __hip_bfloat16 h = __float2bfloat16(x);
    return *reinterpret_cast<short*>(&h);
}
__device__ __forceinline__ float bf2f(unsigned short u) {
    union { unsigned int i; float f; } x; x.i = ((unsigned)u) << 16; return x.f;
}

// ---- prep: swb (mix B-panel) + dwb (pconv B-fragments), both bf16 --------
__global__ __launch_bounds__(256) void prep_k(const float* __restrict__ sw,
                                              const float* __restrict__ dw,
                                              short* __restrict__ swb,
                                              short* __restrict__ dwb) {
    int t = threadIdx.x;
#pragma unroll
    for (int j = 0; j < 10; ++j) {          // 64*BST = 2560 cells
        int cell = t + j * 256;
        if (cell < 64 * BST) {
            int ch = cell / BST, k = cell % BST;
            float v = (k < KF) ? sw[k * 64 + ch] : 0.f;
            swb[cell] = f2bf(v);
        }
    }
#pragma unroll
    for (int p4 = 0; p4 < 4; ++p4) {        // 1024 (frag,lane) pairs
        int p = t + p4 * 256;
        int frag = p >> 6, lane = p & 63;
        int nb = frag >> 3, tt = (frag >> 1) & 3, kk = frag & 1;
        int col = nb * 64 + tt * 16 + (lane & 15);
#pragma unroll
        for (int j = 0; j < 8; ++j) {
            int k = kk * 32 + (lane >> 4) * 8 + j;
            dwb[(size_t)p * 8 + j] = f2bf(dw[k * 128 + col]);
        }
    }
}

// ---- Kernel: MFMA spatial mix + coalesced elementwise + XCD-local adj ----
__global__ __launch_bounds__(256) void mix_k(
    const float* __restrict__ inputs,   // [NF,64]
    const float* __restrict__ filt,     // [NF,27]
    const int*   __restrict__ face,     // [NF,3]
    const short* __restrict__ swb,      // [64][BST] bf16 (prepped)
    __hip_bfloat16* __restrict__ contrib, // [NF,64]
    int* __restrict__ adjc,             // [NCPY][NV][8]: [count|f0..f6]
    int* __restrict__ ovf,              // [OVF_CAP][2] (v,f)
    int* __restrict__ ovf_cnt)
{
    __shared__ __align__(16) char smem[16384];
    short* Af = (short*)smem;                 // 64*LST*2 = 7168 B
    short* Bs = (short*)(smem + 7168);        // 64*BST*2 = 5120 B
    float (*Wt)[64] = (float (*)[64])smem;    // phase 2 reuse: 16384 B

    const int t  = threadIdx.x;
    const int fb = blockIdx.x * 64;
    const int cp = blockIdx.x & (NCPY - 1);   // XCD-local under round-robin

    if (t < 192) {
        int fl = t / 3, vi = t - fl * 3;
        int v = face[(size_t)(fb + fl) * 3 + vi];
        int* row = adjc + ((size_t)cp * NVERT + v) * 8;
        int s = atomicAdd(row, 1);
        if (s < 7) row[1 + s] = fb + fl;       // same 32B line as the count
        else {
            int pos = atomicAdd(ovf_cnt, 1);
            if (pos < OVF_CAP) { ovf[pos * 2] = v; ovf[pos * 2 + 1] = fb + fl; }
        }
    }

    for (int i = t; i < 320; i += 256)
        ((float4*)Bs)[i] = ((const float4*)swb)[i];
#pragma unroll
    for (int j = 0; j < 4; ++j) {
        int idx = t + j * 256;                // 64 faces * 16 k-pairs
        int fl = idx >> 4, k = (idx & 15) * 2;
        const float* fr = filt + (size_t)(fb + fl) * KF;
        float v0 = (k     < KF) ? fr[k]     : 0.f;
        float v1 = (k + 1 < KF) ? fr[k + 1] : 0.f;
        Af[fl * LST + k]     = f2bf(v0);
        Af[fl * LST + k + 1] = f2bf(v1);
    }
    __syncthreads();

    const int lane = t & 63;
    const int wid  = t >> 6;
    const int r0   = wid * 16;

    bf16x8 a = *(const bf16x8*)&Af[(r0 + (lane & 15)) * LST + (lane >> 4) * 8];
    f32x4 acc[4];
#pragma unroll
    for (int cb = 0; cb < 4; ++cb) {
        bf16x8 b = *(const bf16x8*)&Bs[(cb * 16 + (lane & 15)) * BST + (lane >> 4) * 8];
        acc[cb] = __builtin_amdgcn_mfma_f32_16x16x32_bf16(a, b, (f32x4){0.f, 0.f, 0.f, 0.f}, 0, 0, 0);
    }
    __syncthreads();

#pragma unroll
    for (int cb = 0; cb < 4; ++cb)
#pragma unroll
        for (int i = 0; i < 4; ++i)
            Wt[r0 + (lane >> 4) * 4 + i][cb * 16 + (lane & 15)] = acc[cb][i];
    __syncthreads();

#pragma unroll
    for (int p = 0; p < 4; ++p) {
        int idx = (p * 256 + t) * 4;
        int fl = idx >> 6, c = idx & 63;
        float4 in4 = *(const float4*)&inputs[(size_t)(fb + fl) * 64 + c];
        float4 w4  = *(const float4*)&Wt[fl][c];
        short4 o;
        o.x = f2bf(in4.x * w4.x);
        o.y = f2bf(in4.y * w4.y);
        o.z = f2bf(in4.z * w4.z);
        o.w = f2bf(in4.w * w4.w);
        *(short4*)((short*)contrib + (size_t)fb * 64 + idx) = o;
    }
}

// ---- pconv: gather (8 local copies) + MFMA conv + bias + ReLU + stats ----
#define BV 32
__global__ __launch_bounds__(256) void pconv_k(
    const __hip_bfloat16* __restrict__ contrib, // [NF,64]
    const int* __restrict__ adjc,               // [NCPY][NV][8]
    const int* __restrict__ ovf,                // [OVF_CAP][2]
    const int* __restrict__ ovf_cnt,
    const int* __restrict__ nf_count,           // [NV]
    const int* __restrict__ vt_map,             // [NV] (int32)
    const short* __restrict__ dwb,              // prepped dw fragments
    const float* __restrict__ bias,             // [128]
    __hip_bfloat16* __restrict__ outb,          // [NV,128] bf16 (ws)
    float* __restrict__ stats)                  // [8][256]
{
    __shared__ int   srcL[BV];
    __shared__ float denL[BV];
    __shared__ int   adjL[NCPY][BV][8];            // 8 KB
    __shared__ int   flatL[BV][26];                // merged face lists
    __shared__ int   fcnt[BV];
    __shared__ __align__(16) short A[BV * 64];     // swizzled bf16 A-tile, 4KB
    __shared__ __align__(16) short outL[BV * 128]; // C-tile bf16, 8KB

    const int t     = threadIdx.x;
    const int lane  = t & 63;
    const int wid   = t >> 6;
    const int vbase = blockIdx.x * BV;

    if (t < BV) {
        int src = vt_map[vbase + t];
        srcL[t] = src;
        denL[t] = 1.f / (float)max(nf_count[src], 1);
    }
    __syncthreads();
    // stage all copies' rows: 2048 ints, coalesced per copy region
#pragma unroll
    for (int r = 0; r < 8; ++r) {
        int i = t + r * 256;
        int copy = i >> 8, row = (i >> 3) & 31, j = i & 7;
        adjL[copy][row][j] = adjc[((size_t)copy * NVERT + srcL[row]) * 8 + j];
    }
    __syncthreads();

    // compact to flat per-vertex lists (+ rare overflow merge)
    if (t < BV) {
        int cnt = 0;
#pragma unroll
        for (int copy = 0; copy < NCPY; ++copy) {
            int n = adjL[copy][t][0];
            n = n > 7 ? 7 : n;
            for (int j = 0; j < n; ++j)
                if (cnt < 26) flatL[t][cnt++] = adjL[copy][t][1 + j];
        }
        int oc = *ovf_cnt;
        oc = oc > OVF_CAP ? OVF_CAP : oc;
        for (int j = 0; j < oc; ++j)
            if (ovf[2 * j] == srcL[t] && cnt < 26) flatL[t][cnt++] = ovf[2 * j + 1];
        fcnt[t] = cnt;
    }
    __syncthreads();

    // ---- gather: wave wid produces rows [wid*8, wid*8+8); lane = k-channel
    for (int q0 = 0; q0 < 8; ++q0) {
        int q = wid * 8 + q0;
        int n = fcnt[q];
        float acc = 0.f;
        int j = 0;
        for (; j + 4 <= n; j += 4) {
            int f0 = flatL[q][j + 0];
            int f1 = flatL[q][j + 1];
            int f2 = flatL[q][j + 2];
            int f3 = flatL[q][j + 3];
            float a0 = __bfloat162float(contrib[(size_t)f0 * 64 + lane]);
            float a1 = __bfloat162float(contrib[(size_t)f1 * 64 + lane]);
            float a2 = __bfloat162float(contrib[(size_t)f2 * 64 + lane]);
            float a3 = __bfloat162float(contrib[(size_t)f3 * 64 + lane]);
            acc += (a0 + a1) + (a2 + a3);
        }
        for (; j < n; ++j) {
            int f = flatL[q][j];
            acc += __bfloat162float(contrib[(size_t)f * 64 + lane]);
        }
        acc *= denL[q];
        int swz = (lane & 7) | ((((lane >> 3) ^ (q & 7))) << 3);
        A[q * 64 + swz] = f2bf(acc);
    }
    __syncthreads();

    // ---- MFMA matmul: wave (mi, nb): mi = wid&1 (16 rows), nb = wid>>1
    const int mi = wid & 1;
    const int nb = wid >> 1;
    f32x4 acc[4];
#pragma unroll
    for (int tt = 0; tt < 4; ++tt) acc[tt] = (f32x4){0.f, 0.f, 0.f, 0.f};
#pragma unroll
    for (int kk = 0; kk < 2; ++kk) {
        int row = mi * 16 + (lane & 15);
        int chunk = (kk * 4 + (lane >> 4)) ^ (row & 7);
        bf16x8 a = *(const bf16x8*)&A[row * 64 + chunk * 8];
#pragma unroll
        for (int tt = 0; tt < 4; ++tt) {
            int frag = (nb * 4 + tt) * 2 + kk;
            bf16x8 b = *(const bf16x8*)&dwb[((size_t)frag * 64 + lane) * 8];
            acc[tt] = __builtin_amdgcn_mfma_f32_16x16x32_bf16(a, b, acc[tt], 0, 0, 0);
        }
    }

    // bias + ReLU + C-tile to LDS + BN stats
    float* st = stats + (blockIdx.x & 7) * 256;
#pragma unroll
    for (int tt = 0; tt < 4; ++tt) {
        int col = nb * 64 + tt * 16 + (lane & 15);
        float bv = bias[col];
        float s = 0.f, s2 = 0.f;
#pragma unroll
        for (int i = 0; i < 4; ++i) {
            float o = fmaxf(acc[tt][i] + bv, 0.f);
            int row = mi * 16 + (lane >> 4) * 4 + i;
            outL[row * 128 + col] = f2bf(o);
            s  += o;
            s2 += o * o;
        }
        s  += __shfl_xor(s, 16);  s  += __shfl_xor(s, 32);
        s2 += __shfl_xor(s2, 16); s2 += __shfl_xor(s2, 32);
        if ((lane >> 4) == 0) {
            atomicAdd(&st[col], s);
            atomicAdd(&st[128 + col], s2);
        }
    }
    __syncthreads();

#pragma unroll
    for (int r = 0; r < 2; ++r) {
        int i = t + r * 256;
        ((int4*)&outb[(size_t)vbase * 128])[i] = ((const int4*)outL)[i];
    }
}

// ---- BatchNorm finalize: bf16 in (ws) -> f32 out (d_out) -----------------
__global__ __launch_bounds__(256) void bn_k(
    const __hip_bfloat16* __restrict__ outb,
    float* __restrict__ out,
    const float* __restrict__ stats,
    const float* __restrict__ gamma,
    const float* __restrict__ beta)
{
    __shared__ float sc[128], sh[128];
    if (threadIdx.x < 128) {
        int c = threadIdx.x;
        float s = 0.f, s2 = 0.f;
#pragma unroll
        for (int r = 0; r < 8; ++r) {
            s  += stats[r * 256 + c];
            s2 += stats[r * 256 + 128 + c];
        }
        float mean = s / (float)NVERT;
        float var  = s2 / (float)NVERT - mean * mean;
        float inv  = rsqrtf(var + BN_EPS) * gamma[c];
        sc[c] = inv;
        sh[c] = beta[c] - mean * inv;
    }
    __syncthreads();

    const unsigned short* ob = (const unsigned short*)outb;
    float4* o4 = (float4*)out;
    size_t total4 = (size_t)NVERT * COUT / 4;
    for (size_t i = (size_t)blockIdx.x * 256 + threadIdx.x; i < total4;
         i += (size_t)gridDim.x * 256) {
        int c0 = (int)((i * 4) & 127);
        ushort4 u = *(const ushort4*)&ob[i * 4];
        float4 v;
        v.x = bf2f(u.x) * sc[c0 + 0] + sh[c0 + 0];
        v.y = bf2f(u.y) * sc[c0 + 1] + sh[c0 + 1];
        v.z = bf2f(u.z) * sc[c0 + 2] + sh[c0 + 2];
        v.w = bf2f(u.w) * sc[c0 + 3] + sh[c0 + 3];
        o4[i] = v;
    }
}

extern "C" void kernel_launch(void* const* d_in, const int* in_sizes, int n_in,
                              void* d_out, int out_size, void* d_ws, size_t ws_size,
                              hipStream_t stream) {
    const float* inputs   = (const float*)d_in[0];
    const float* filt     = (const float*)d_in[1];
    const int*   face     = (const int*)d_in[2];
    const int*   nf_count = (const int*)d_in[3];
    const int*   vt_map   = (const int*)d_in[4];
    const float* sw       = (const float*)d_in[5];
    const float* dw       = (const float*)d_in[6];
    const float* bias     = (const float*)d_in[7];
    const float* gamma    = (const float*)d_in[8];
    const float* beta     = (const float*)d_in[9];
    float* out = (float*)d_out;

    // ws layout:
    //   [stats 8192][ovf_cnt 64][ovf 32768][swb 5120][dwb 16384][outb 51.2MB]
    char* w = (char*)d_ws;
    float*          stats  = (float*)w;
    int*            ovfcnt = (int*)(w + 8192);
    int*            ovf    = (int*)(w + 8192 + 64);
    short*          swb    = (short*)(w + 8192 + 64 + OVF_CAP * 8);
    short*          dwb    = (short*)(w + 8192 + 64 + OVF_CAP * 8 + 5120);
    __hip_bfloat16* outb   = (__hip_bfloat16*)(w + 8192 + 64 + OVF_CAP * 8 + 5120 + 16384);

    // d_out staging (dead before bn_k writes):
    //   [contrib bf16 51.2MB][adjc 51.2MB] = 102.4MB exactly
    __hip_bfloat16* contrib = (__hip_bfloat16*)d_out;
    int* adjc = (int*)((char*)d_out + (size_t)NFACE * CIN * 2);

    hipMemsetAsync(d_ws, 0, 8192 + 64, stream);                       // stats + ovf_cnt
    hipMemsetAsync(adjc, 0, (size_t)NCPY * NVERT * 8 * 4, stream);    // counts

    prep_k<<<1, 256, 0, stream>>>(sw, dw, swb, dwb);
    mix_k<<<NFACE / 64, 256, 0, stream>>>(inputs, filt, face, swb,
                                          contrib, adjc, ovf, ovfcnt);
    pconv_k<<<NVERT / BV, 256, 0, stream>>>(contrib, adjc, ovf, ovfcnt,
                                            nf_count, vt_map, dwb, bias,
                                            outb, stats);
    bn_k<<<2048, 256, 0, stream>>>(outb, out, stats, gamma, beta);
}

// Round 13
// 230.261 us; speedup vs baseline: 1.1227x; 1.1227x over previous
//
#include <hip/hip_runtime.h>
#include <hip/hip_bf16.h>

#define NFACE 400000
#define NVERT 200000
#define CIN 64
#define COUT 128
#define KF 27
#define BN_EPS 1e-5f
#define LST 56            // Af row stride (shorts): 112B, bank-spread
#define BST 40            // Bs/swb row stride (shorts): 80B, bank-spread

#define M_TOT (NFACE * 3)            // 1.2M incidences
#define NB    391                    // coarse buckets: v>>9  (200000>>9 = 390)
#define NBLK  256                    // blocks for hist/scatter
#define CHUNK ((M_TOT + NBLK - 1) / NBLK)   // 4688

typedef __attribute__((ext_vector_type(8))) short bf16x8;
typedef __attribute__((ext_vector_type(4))) float f32x4;

__device__ __forceinline__ short f2bf(float x) {
    __hip_bfloat16 h = __float2bfloat16(x);
    return *reinterpret_cast<short*>(&h);
}
__device__ __forceinline__ float bf2f(unsigned short u) {
    union { unsigned int i; float f; } x; x.i = ((unsigned)u) << 16; return x.f;
}

// ---- prep: swb (mix B-panel) + dwb (pconv B-fragments), both bf16 --------
__global__ __launch_bounds__(256) void prep_k(const float* __restrict__ sw,
                                              const float* __restrict__ dw,
                                              short* __restrict__ swb,
                                              short* __restrict__ dwb) {
    int t = threadIdx.x;
#pragma unroll
    for (int j = 0; j < 10; ++j) {
        int cell = t + j * 256;
        if (cell < 64 * BST) {
            int ch = cell / BST, k = cell % BST;
            float v = (k < KF) ? sw[k * 64 + ch] : 0.f;
            swb[cell] = f2bf(v);
        }
    }
#pragma unroll
    for (int p4 = 0; p4 < 4; ++p4) {
        int p = t + p4 * 256;
        int frag = p >> 6, lane = p & 63;
        int nb = frag >> 3, tt = (frag >> 1) & 3, kk = frag & 1;
        int col = nb * 64 + tt * 16 + (lane & 15);
#pragma unroll
        for (int j = 0; j < 8; ++j) {
            int k = kk * 32 + (lane >> 4) * 8 + j;
            dwb[(size_t)p * 8 + j] = f2bf(dw[k * 128 + col]);
        }
    }
}

// ---- sort pass A: per-(block,bucket) histogram ---------------------------
__global__ __launch_bounds__(256) void hist_k(const int* __restrict__ faceflat,
                                              int* __restrict__ blockcnt) {
    __shared__ int h[512];
    const int t = threadIdx.x, blk = blockIdx.x;
    for (int j = t; j < 512; j += 256) h[j] = 0;
    __syncthreads();
    int e0 = blk * CHUNK;
    int e1 = min(e0 + CHUNK, M_TOT);
    for (int e = e0 + t; e < e1; e += 256)
        atomicAdd(&h[faceflat[e] >> 9], 1);
    __syncthreads();
    for (int j = t; j < 512; j += 256) blockcnt[blk * 512 + j] = h[j];
}

// ---- sort pass B: totals, exclusive scan, rebase per-block bases ---------
__global__ __launch_bounds__(256) void scan_k(int* __restrict__ blockcnt,
                                              int* __restrict__ bucket_start,
                                              int* __restrict__ row_off) {
    __shared__ int tot[512];
    __shared__ int bst[512];
    const int t = threadIdx.x;
    for (int b = t; b < 512; b += 256) {
        int acc = 0;
        if (b < NB)
            for (int k = 0; k < NBLK; ++k) acc += blockcnt[k * 512 + b];
        tot[b] = acc;
    }
    __syncthreads();
    if (t < 64) {                      // wave-0 exclusive scan of 512 entries
        int base8 = t * 8, loc[8], s = 0;
#pragma unroll
        for (int j = 0; j < 8; ++j) { loc[j] = s; s += tot[base8 + j]; }
        int v = s;
        for (int off = 1; off < 64; off <<= 1) {
            int u = __shfl_up(v, off);
            if (t >= off) v += u;
        }
        int excl = v - s;
#pragma unroll
        for (int j = 0; j < 8; ++j) bst[base8 + j] = excl + loc[j];
    }
    __syncthreads();
    for (int b = t; b < NB; b += 256) bucket_start[b] = bst[b];
    if (t == 0) { bucket_start[NB] = bst[NB]; row_off[NVERT] = M_TOT; }
    for (int b = t; b < NB; b += 256) {
        int acc = bst[b];
        for (int k = 0; k < NBLK; ++k) {
            int c = blockcnt[k * 512 + b];
            blockcnt[k * 512 + b] = acc;
            acc += c;
        }
    }
}

// ---- sort pass C: scatter pairs into bucket-major order ------------------
__global__ __launch_bounds__(256) void scat_k(const int* __restrict__ faceflat,
                                              const int* __restrict__ blockcnt,
                                              int2* __restrict__ pairs) {
    __shared__ int baseL[512];
    __shared__ int lc[512];
    const int t = threadIdx.x, blk = blockIdx.x;
    for (int j = t; j < 512; j += 256) { baseL[j] = blockcnt[blk * 512 + j]; lc[j] = 0; }
    __syncthreads();
    int e0 = blk * CHUNK;
    int e1 = min(e0 + CHUNK, M_TOT);
    for (int e = e0 + t; e < e1; e += 256) {
        int v = faceflat[e];
        int b = v >> 9;
        int l = atomicAdd(&lc[b], 1);
        pairs[baseL[b] + l] = make_int2(v, e / 3);
    }
}

// ---- sort pass D: per-bucket CSR build (LDS count + scan + place) --------
__global__ __launch_bounds__(256) void csr_k(const int2* __restrict__ pairs,
                                             const int* __restrict__ bucket_start,
                                             int* __restrict__ row_off,
                                             int* __restrict__ csr) {
    __shared__ int cnt[512], esc[512], pc[512];
    const int t = threadIdx.x, b = blockIdx.x;
    const int p0 = bucket_start[b], p1 = bucket_start[b + 1];
    const int vbase = b << 9;
    for (int j = t; j < 512; j += 256) { cnt[j] = 0; pc[j] = 0; }
    __syncthreads();
    for (int i = p0 + t; i < p1; i += 256)
        atomicAdd(&cnt[pairs[i].x - vbase], 1);
    __syncthreads();
    if (t < 64) {
        int base8 = t * 8, loc[8], s = 0;
#pragma unroll
        for (int j = 0; j < 8; ++j) { loc[j] = s; s += cnt[base8 + j]; }
        int v = s;
        for (int off = 1; off < 64; off <<= 1) {
            int u = __shfl_up(v, off);
            if (t >= off) v += u;
        }
        int excl = v - s;
#pragma unroll
        for (int j = 0; j < 8; ++j) esc[base8 + j] = excl + loc[j];
    }
    __syncthreads();
    int nvb = min(512, NVERT - vbase);
    for (int j = t; j < nvb; j += 256) row_off[vbase + j] = p0 + esc[j];
    for (int i = p0 + t; i < p1; i += 256) {
        int lv = pairs[i].x - vbase;
        int l = atomicAdd(&pc[lv], 1);
        csr[p0 + esc[lv] + l] = pairs[i].y;
    }
}

// ---- Kernel: MFMA spatial mix + coalesced elementwise (no scatter) -------
__global__ __launch_bounds__(256) void mix_k(
    const float* __restrict__ inputs,   // [NF,64]
    const float* __restrict__ filt,     // [NF,27]
    const short* __restrict__ swb,      // [64][BST] bf16 (prepped)
    __hip_bfloat16* __restrict__ contrib) // [NF,64]
{
    __shared__ __align__(16) char smem[16384];
    short* Af = (short*)smem;                 // 64*LST*2 = 7168 B
    short* Bs = (short*)(smem + 7168);        // 64*BST*2 = 5120 B
    float (*Wt)[64] = (float (*)[64])smem;    // phase 2 reuse: 16384 B

    const int t  = threadIdx.x;
    const int fb = blockIdx.x * 64;

    for (int i = t; i < 320; i += 256)
        ((float4*)Bs)[i] = ((const float4*)swb)[i];
#pragma unroll
    for (int j = 0; j < 4; ++j) {
        int idx = t + j * 256;
        int fl = idx >> 4, k = (idx & 15) * 2;
        const float* fr = filt + (size_t)(fb + fl) * KF;
        float v0 = (k     < KF) ? fr[k]     : 0.f;
        float v1 = (k + 1 < KF) ? fr[k + 1] : 0.f;
        Af[fl * LST + k]     = f2bf(v0);
        Af[fl * LST + k + 1] = f2bf(v1);
    }
    __syncthreads();

    const int lane = t & 63;
    const int wid  = t >> 6;
    const int r0   = wid * 16;

    bf16x8 a = *(const bf16x8*)&Af[(r0 + (lane & 15)) * LST + (lane >> 4) * 8];
    f32x4 acc[4];
#pragma unroll
    for (int cb = 0; cb < 4; ++cb) {
        bf16x8 b = *(const bf16x8*)&Bs[(cb * 16 + (lane & 15)) * BST + (lane >> 4) * 8];
        acc[cb] = __builtin_amdgcn_mfma_f32_16x16x32_bf16(a, b, (f32x4){0.f, 0.f, 0.f, 0.f}, 0, 0, 0);
    }
    __syncthreads();

#pragma unroll
    for (int cb = 0; cb < 4; ++cb)
#pragma unroll
        for (int i = 0; i < 4; ++i)
            Wt[r0 + (lane >> 4) * 4 + i][cb * 16 + (lane & 15)] = acc[cb][i];
    __syncthreads();

#pragma unroll
    for (int p = 0; p < 4; ++p) {
        int idx = (p * 256 + t) * 4;
        int fl = idx >> 6, c = idx & 63;
        float4 in4 = *(const float4*)&inputs[(size_t)(fb + fl) * 64 + c];
        float4 w4  = *(const float4*)&Wt[fl][c];
        short4 o;
        o.x = f2bf(in4.x * w4.x);
        o.y = f2bf(in4.y * w4.y);
        o.z = f2bf(in4.z * w4.z);
        o.w = f2bf(in4.w * w4.w);
        *(short4*)((short*)contrib + (size_t)fb * 64 + idx) = o;
    }
}

// ---- pconv: CSR gather + MFMA conv + bias + ReLU + BN stats --------------
#define BV 32
__global__ __launch_bounds__(256) void pconv_k(
    const __hip_bfloat16* __restrict__ contrib, // [NF,64]
    const int* __restrict__ row_off,            // [NV+1]
    const int* __restrict__ csr,                // [M]
    const int* __restrict__ nf_count,           // [NV]
    const int* __restrict__ vt_map,             // [NV] (int32)
    const short* __restrict__ dwb,              // prepped dw fragments
    const float* __restrict__ bias,             // [128]
    __hip_bfloat16* __restrict__ outb,          // [NV,128] bf16 (ws)
    float* __restrict__ stats)                  // [8][256]
{
    __shared__ float denL[BV];
    __shared__ int   offL[BV];
    __shared__ int   degL[BV];
    __shared__ int   flatL[BV][32];                // 4 KB
    __shared__ __align__(16) short A[BV * 64];     // swizzled bf16 A-tile, 4KB
    __shared__ __align__(16) short outL[BV * 128]; // C-tile bf16, 8KB

    const int t     = threadIdx.x;
    const int lane  = t & 63;
    const int wid   = t >> 6;
    const int vbase = blockIdx.x * BV;

    if (t < BV) {
        int src = vt_map[vbase + t];
        denL[t] = 1.f / (float)max(nf_count[src], 1);
        int o = row_off[src];
        int d = row_off[src + 1] - o;
        offL[t] = o;
        degL[t] = d > 32 ? 32 : d;
    }
    __syncthreads();
    // stage face lists: 1024 slots, 4 per thread
#pragma unroll
    for (int r = 0; r < 4; ++r) {
        int i = t + r * 256;
        int row = i >> 5, j = i & 31;
        if (j < degL[row]) flatL[row][j] = csr[offL[row] + j];
    }
    __syncthreads();

    // ---- gather: wave wid produces rows [wid*8, wid*8+8); lane = k-channel
    for (int q0 = 0; q0 < 8; ++q0) {
        int q = wid * 8 + q0;
        int n = degL[q];
        float acc = 0.f;
        int j = 0;
        for (; j + 4 <= n; j += 4) {
            int f0 = flatL[q][j + 0];
            int f1 = flatL[q][j + 1];
            int f2 = flatL[q][j + 2];
            int f3 = flatL[q][j + 3];
            float a0 = __bfloat162float(contrib[(size_t)f0 * 64 + lane]);
            float a1 = __bfloat162float(contrib[(size_t)f1 * 64 + lane]);
            float a2 = __bfloat162float(contrib[(size_t)f2 * 64 + lane]);
            float a3 = __bfloat162float(contrib[(size_t)f3 * 64 + lane]);
            acc += (a0 + a1) + (a2 + a3);
        }
        for (; j < n; ++j) {
            int f = flatL[q][j];
            acc += __bfloat162float(contrib[(size_t)f * 64 + lane]);
        }
        acc *= denL[q];
        int swz = (lane & 7) | ((((lane >> 3) ^ (q & 7))) << 3);
        A[q * 64 + swz] = f2bf(acc);
    }
    __syncthreads();

    // ---- MFMA matmul: wave (mi, nb): mi = wid&1 (16 rows), nb = wid>>1
    const int mi = wid & 1;
    const int nb = wid >> 1;
    f32x4 acc[4];
#pragma unroll
    for (int tt = 0; tt < 4; ++tt) acc[tt] = (f32x4){0.f, 0.f, 0.f, 0.f};
#pragma unroll
    for (int kk = 0; kk < 2; ++kk) {
        int row = mi * 16 + (lane & 15);
        int chunk = (kk * 4 + (lane >> 4)) ^ (row & 7);
        bf16x8 a = *(const bf16x8*)&A[row * 64 + chunk * 8];
#pragma unroll
        for (int tt = 0; tt < 4; ++tt) {
            int frag = (nb * 4 + tt) * 2 + kk;
            bf16x8 b = *(const bf16x8*)&dwb[((size_t)frag * 64 + lane) * 8];
            acc[tt] = __builtin_amdgcn_mfma_f32_16x16x32_bf16(a, b, acc[tt], 0, 0, 0);
        }
    }

    // bias + ReLU + C-tile to LDS + BN stats
    float* st = stats + (blockIdx.x & 7) * 256;
#pragma unroll
    for (int tt = 0; tt < 4; ++tt) {
        int col = nb * 64 + tt * 16 + (lane & 15);
        float bv = bias[col];
        float s = 0.f, s2 = 0.f;
#pragma unroll
        for (int i = 0; i < 4; ++i) {
            float o = fmaxf(acc[tt][i] + bv, 0.f);
            int row = mi * 16 + (lane >> 4) * 4 + i;
            outL[row * 128 + col] = f2bf(o);
            s  += o;
            s2 += o * o;
        }
        s  += __shfl_xor(s, 16);  s  += __shfl_xor(s, 32);
        s2 += __shfl_xor(s2, 16); s2 += __shfl_xor(s2, 32);
        if ((lane >> 4) == 0) {
            atomicAdd(&st[col], s);
            atomicAdd(&st[128 + col], s2);
        }
    }
    __syncthreads();

#pragma unroll
    for (int r = 0; r < 2; ++r) {
        int i = t + r * 256;
        ((int4*)&outb[(size_t)vbase * 128])[i] = ((const int4*)outL)[i];
    }
}

// ---- BatchNorm finalize: bf16 in (ws) -> f32 out (d_out) -----------------
__global__ __launch_bounds__(256) void bn_k(
    const __hip_bfloat16* __restrict__ outb,
    float* __restrict__ out,
    const float* __restrict__ stats,
    const float* __restrict__ gamma,
    const float* __restrict__ beta)
{
    __shared__ float sc[128], sh[128];
    if (threadIdx.x < 128) {
        int c = threadIdx.x;
        float s = 0.f, s2 = 0.f;
#pragma unroll
        for (int r = 0; r < 8; ++r) {
            s  += stats[r * 256 + c];
            s2 += stats[r * 256 + 128 + c];
        }
        float mean = s / (float)NVERT;
        float var  = s2 / (float)NVERT - mean * mean;
        float inv  = rsqrtf(var + BN_EPS) * gamma[c];
        sc[c] = inv;
        sh[c] = beta[c] - mean * inv;
    }
    __syncthreads();

    const unsigned short* ob = (const unsigned short*)outb;
    float4* o4 = (float4*)out;
    size_t total4 = (size_t)NVERT * COUT / 4;
    for (size_t i = (size_t)blockIdx.x * 256 + threadIdx.x; i < total4;
         i += (size_t)gridDim.x * 256) {
        int c0 = (int)((i * 4) & 127);
        ushort4 u = *(const ushort4*)&ob[i * 4];
        float4 v;
        v.x = bf2f(u.x) * sc[c0 + 0] + sh[c0 + 0];
        v.y = bf2f(u.y) * sc[c0 + 1] + sh[c0 + 1];
        v.z = bf2f(u.z) * sc[c0 + 2] + sh[c0 + 2];
        v.w = bf2f(u.w) * sc[c0 + 3] + sh[c0 + 3];
        o4[i] = v;
    }
}

extern "C" void kernel_launch(void* const* d_in, const int* in_sizes, int n_in,
                              void* d_out, int out_size, void* d_ws, size_t ws_size,
                              hipStream_t stream) {
    const float* inputs   = (const float*)d_in[0];
    const float* filt     = (const float*)d_in[1];
    const int*   face     = (const int*)d_in[2];
    const int*   nf_count = (const int*)d_in[3];
    const int*   vt_map   = (const int*)d_in[4];
    const float* sw       = (const float*)d_in[5];
    const float* dw       = (const float*)d_in[6];
    const float* bias     = (const float*)d_in[7];
    const float* gamma    = (const float*)d_in[8];
    const float* beta     = (const float*)d_in[9];
    float* out = (float*)d_out;

    // ws: [stats 8KB][swb 8KB][dwb 16KB][outb bf16 51.2MB]  (R11 layout)
    char* w = (char*)d_ws;
    float*          stats = (float*)w;
    short*          swb   = (short*)(w + 8192);
    short*          dwb   = (short*)(w + 16384);
    __hip_bfloat16* outb  = (__hip_bfloat16*)(w + 32768);

    // d_out staging (all dead before bn_k writes d_out):
    //   [contrib 51.2MB][pairs 9.6MB][csr 4.8MB][row_off 0.8MB]
    //   [blockcnt 512KB][bucket_start 2KB]  = ~67MB < 102.4MB
    char* o = (char*)d_out;
    __hip_bfloat16* contrib      = (__hip_bfloat16*)o;
    int2*           pairs        = (int2*)(o + 51200000);
    int*            csr          = (int*)(o + 60800000);
    int*            row_off      = (int*)(o + 65600000);
    int*            blockcnt     = (int*)(o + 66400256);
    int*            bucket_start = (int*)(o + 66924544);
    const int*      faceflat     = face;

    hipMemsetAsync(stats, 0, 8192, stream);

    prep_k<<<1, 256, 0, stream>>>(sw, dw, swb, dwb);
    hist_k<<<NBLK, 256, 0, stream>>>(faceflat, blockcnt);
    scan_k<<<1, 256, 0, stream>>>(blockcnt, bucket_start, row_off);
    scat_k<<<NBLK, 256, 0, stream>>>(faceflat, blockcnt, pairs);
    csr_k<<<NB, 256, 0, stream>>>(pairs, bucket_start, row_off, csr);
    mix_k<<<NFACE / 64, 256, 0, stream>>>(inputs, filt, swb, contrib);
    pconv_k<<<NVERT / BV, 256, 0, stream>>>(contrib, row_off, csr, nf_count,
                                            vt_map, dwb, bias, outb, stats);
    bn_k<<<2048, 256, 0, stream>>>(outb, out, stats, gamma, beta);
}

// Round 14
// 190.107 us; speedup vs baseline: 1.3599x; 1.2112x over previous
//
#include <hip/hip_runtime.h>
#include <hip/hip_bf16.h>

#define NFACE 400000
#define NVERT 200000
#define CIN 64
#define COUT 128
#define KF 27
#define BN_EPS 1e-5f
#define LST 56            // Af row stride (shorts): 112B, bank-spread
#define BST 40            // Bs/swb row stride (shorts): 80B, bank-spread

#define M_TOT (NFACE * 3)            // 1.2M incidences
#define NB    391                    // coarse buckets: v>>9
#define NBLK  256                    // blocks for hist/scatter
#define CHUNK ((M_TOT + NBLK - 1) / NBLK)   // 4688

typedef __attribute__((ext_vector_type(8))) short bf16x8;
typedef __attribute__((ext_vector_type(4))) float f32x4;

__device__ __forceinline__ short f2bf(float x) {
    __hip_bfloat16 h = __float2bfloat16(x);
    return *reinterpret_cast<short*>(&h);
}
__device__ __forceinline__ float bf2f(unsigned short u) {
    union { unsigned int i; float f; } x; x.i = ((unsigned)u) << 16; return x.f;
}

// ---- prep: swb (mix B-panel) + dwb (pconv B-fragments), both bf16 --------
__global__ __launch_bounds__(256) void prep_k(const float* __restrict__ sw,
                                              const float* __restrict__ dw,
                                              short* __restrict__ swb,
                                              short* __restrict__ dwb) {
    int t = threadIdx.x;
#pragma unroll
    for (int j = 0; j < 10; ++j) {
        int cell = t + j * 256;
        if (cell < 64 * BST) {
            int ch = cell / BST, k = cell % BST;
            float v = (k < KF) ? sw[k * 64 + ch] : 0.f;
            swb[cell] = f2bf(v);
        }
    }
#pragma unroll
    for (int p4 = 0; p4 < 4; ++p4) {
        int p = t + p4 * 256;
        int frag = p >> 6, lane = p & 63;
        int nb = frag >> 3, tt = (frag >> 1) & 3, kk = frag & 1;
        int col = nb * 64 + tt * 16 + (lane & 15);
#pragma unroll
        for (int j = 0; j < 8; ++j) {
            int k = kk * 32 + (lane >> 4) * 8 + j;
            dwb[(size_t)p * 8 + j] = f2bf(dw[k * 128 + col]);
        }
    }
}

// ---- sort pass A: per-(block,bucket) histogram ---------------------------
__global__ __launch_bounds__(256) void hist_k(const int* __restrict__ faceflat,
                                              int* __restrict__ blockcnt) {
    __shared__ int h[512];
    const int t = threadIdx.x, blk = blockIdx.x;
    for (int j = t; j < 512; j += 256) h[j] = 0;
    __syncthreads();
    int e0 = blk * CHUNK;
    int e1 = min(e0 + CHUNK, M_TOT);
    for (int e = e0 + t; e < e1; e += 256)
        atomicAdd(&h[faceflat[e] >> 9], 1);
    __syncthreads();
    for (int j = t; j < 512; j += 256) blockcnt[blk * 512 + j] = h[j];
}

// ---- sort pass B: totals, exclusive scan, rebase per-block bases ---------
__global__ __launch_bounds__(256) void scan_k(int* __restrict__ blockcnt,
                                              int* __restrict__ bucket_start,
                                              int* __restrict__ row_off) {
    __shared__ int tot[512];
    __shared__ int bst[512];
    const int t = threadIdx.x;
    for (int b = t; b < 512; b += 256) {
        int acc = 0;
        if (b < NB)
            for (int k = 0; k < NBLK; ++k) acc += blockcnt[k * 512 + b];
        tot[b] = acc;
    }
    __syncthreads();
    if (t < 64) {
        int base8 = t * 8, loc[8], s = 0;
#pragma unroll
        for (int j = 0; j < 8; ++j) { loc[j] = s; s += tot[base8 + j]; }
        int v = s;
        for (int off = 1; off < 64; off <<= 1) {
            int u = __shfl_up(v, off);
            if (t >= off) v += u;
        }
        int excl = v - s;
#pragma unroll
        for (int j = 0; j < 8; ++j) bst[base8 + j] = excl + loc[j];
    }
    __syncthreads();
    for (int b = t; b < NB; b += 256) bucket_start[b] = bst[b];
    if (t == 0) { bucket_start[NB] = bst[NB]; row_off[NVERT] = M_TOT; }
    for (int b = t; b < NB; b += 256) {
        int acc = bst[b];
        for (int k = 0; k < NBLK; ++k) {
            int c = blockcnt[k * 512 + b];
            blockcnt[k * 512 + b] = acc;
            acc += c;
        }
    }
}

// ---- sort pass C: scatter pairs into bucket-major order ------------------
__global__ __launch_bounds__(256) void scat_k(const int* __restrict__ faceflat,
                                              const int* __restrict__ blockcnt,
                                              int2* __restrict__ pairs) {
    __shared__ int baseL[512];
    __shared__ int lc[512];
    const int t = threadIdx.x, blk = blockIdx.x;
    for (int j = t; j < 512; j += 256) { baseL[j] = blockcnt[blk * 512 + j]; lc[j] = 0; }
    __syncthreads();
    int e0 = blk * CHUNK;
    int e1 = min(e0 + CHUNK, M_TOT);
    for (int e = e0 + t; e < e1; e += 256) {
        int v = faceflat[e];
        int b = v >> 9;
        int l = atomicAdd(&lc[b], 1);
        pairs[baseL[b] + l] = make_int2(v, e / 3);
    }
}

// ---- sort pass D: per-bucket CSR build -----------------------------------
__global__ __launch_bounds__(256) void csr_k(const int2* __restrict__ pairs,
                                             const int* __restrict__ bucket_start,
                                             int* __restrict__ row_off,
                                             int* __restrict__ csr) {
    __shared__ int cnt[512], esc[512], pc[512];
    const int t = threadIdx.x, b = blockIdx.x;
    const int p0 = bucket_start[b], p1 = bucket_start[b + 1];
    const int vbase = b << 9;
    for (int j = t; j < 512; j += 256) { cnt[j] = 0; pc[j] = 0; }
    __syncthreads();
    for (int i = p0 + t; i < p1; i += 256)
        atomicAdd(&cnt[pairs[i].x - vbase], 1);
    __syncthreads();
    if (t < 64) {
        int base8 = t * 8, loc[8], s = 0;
#pragma unroll
        for (int j = 0; j < 8; ++j) { loc[j] = s; s += cnt[base8 + j]; }
        int v = s;
        for (int off = 1; off < 64; off <<= 1) {
            int u = __shfl_up(v, off);
            if (t >= off) v += u;
        }
        int excl = v - s;
#pragma unroll
        for (int j = 0; j < 8; ++j) esc[base8 + j] = excl + loc[j];
    }
    __syncthreads();
    int nvb = min(512, NVERT - vbase);
    for (int j = t; j < nvb; j += 256) row_off[vbase + j] = p0 + esc[j];
    for (int i = p0 + t; i < p1; i += 256) {
        int lv = pairs[i].x - vbase;
        int l = atomicAdd(&pc[lv], 1);
        csr[p0 + esc[lv] + l] = pairs[i].y;
    }
}

// ---- Kernel: MFMA spatial mix + coalesced elementwise (no scatter) -------
__global__ __launch_bounds__(256) void mix_k(
    const float* __restrict__ inputs,   // [NF,64]
    const float* __restrict__ filt,     // [NF,27]
    const short* __restrict__ swb,      // [64][BST] bf16 (prepped)
    __hip_bfloat16* __restrict__ contrib) // [NF,64]
{
    __shared__ __align__(16) char smem[16384];
    short* Af = (short*)smem;                 // 64*LST*2 = 7168 B
    short* Bs = (short*)(smem + 7168);        // 64*BST*2 = 5120 B
    float (*Wt)[64] = (float (*)[64])smem;    // phase 2 reuse: 16384 B

    const int t  = threadIdx.x;
    const int fb = blockIdx.x * 64;

    for (int i = t; i < 320; i += 256)
        ((float4*)Bs)[i] = ((const float4*)swb)[i];
#pragma unroll
    for (int j = 0; j < 4; ++j) {
        int idx = t + j * 256;
        int fl = idx >> 4, k = (idx & 15) * 2;
        const float* fr = filt + (size_t)(fb + fl) * KF;
        float v0 = (k     < KF) ? fr[k]     : 0.f;
        float v1 = (k + 1 < KF) ? fr[k + 1] : 0.f;
        Af[fl * LST + k]     = f2bf(v0);
        Af[fl * LST + k + 1] = f2bf(v1);
    }
    __syncthreads();

    const int lane = t & 63;
    const int wid  = t >> 6;
    const int r0   = wid * 16;

    bf16x8 a = *(const bf16x8*)&Af[(r0 + (lane & 15)) * LST + (lane >> 4) * 8];
    f32x4 acc[4];
#pragma unroll
    for (int cb = 0; cb < 4; ++cb) {
        bf16x8 b = *(const bf16x8*)&Bs[(cb * 16 + (lane & 15)) * BST + (lane >> 4) * 8];
        acc[cb] = __builtin_amdgcn_mfma_f32_16x16x32_bf16(a, b, (f32x4){0.f, 0.f, 0.f, 0.f}, 0, 0, 0);
    }
    __syncthreads();

#pragma unroll
    for (int cb = 0; cb < 4; ++cb)
#pragma unroll
        for (int i = 0; i < 4; ++i)
            Wt[r0 + (lane >> 4) * 4 + i][cb * 16 + (lane & 15)] = acc[cb][i];
    __syncthreads();

#pragma unroll
    for (int p = 0; p < 4; ++p) {
        int idx = (p * 256 + t) * 4;
        int fl = idx >> 6, c = idx & 63;
        float4 in4 = *(const float4*)&inputs[(size_t)(fb + fl) * 64 + c];
        float4 w4  = *(const float4*)&Wt[fl][c];
        short4 o;
        o.x = f2bf(in4.x * w4.x);
        o.y = f2bf(in4.y * w4.y);
        o.z = f2bf(in4.z * w4.z);
        o.w = f2bf(in4.w * w4.w);
        *(short4*)((short*)contrib + (size_t)fb * 64 + idx) = o;
    }
}

// ---- pconv: CSR gather (dual-row, 8-deep MLP) + MFMA conv + stats --------
#define BV 32
__global__ __launch_bounds__(256, 6) void pconv_k(
    const __hip_bfloat16* __restrict__ contrib, // [NF,64]
    const int* __restrict__ row_off,            // [NV+1]
    const int* __restrict__ csr,                // [M]
    const int* __restrict__ nf_count,           // [NV]
    const int* __restrict__ vt_map,             // [NV] (int32)
    const short* __restrict__ dwb,              // prepped dw fragments
    const float* __restrict__ bias,             // [128]
    __hip_bfloat16* __restrict__ outb,          // [NV,128] bf16 (ws)
    float* __restrict__ stats)                  // [8][256]
{
    __shared__ float denL[BV];
    __shared__ int   offL[BV];
    __shared__ int   degL[BV];
    __shared__ int   flatL[BV][32];                // 4 KB (padded with face 0)
    __shared__ __align__(16) short A[BV * 64];     // swizzled bf16 A-tile, 4KB
    __shared__ __align__(16) short outL[BV * 128]; // C-tile bf16, 8KB

    const int t     = threadIdx.x;
    const int lane  = t & 63;
    const int wid   = t >> 6;
    const int vbase = blockIdx.x * BV;
    const unsigned short* ct = (const unsigned short*)contrib;

    if (t < BV) {
        int src = vt_map[vbase + t];
        denL[t] = 1.f / (float)max(nf_count[src], 1);
        int o = row_off[src];
        int d = row_off[src + 1] - o;
        offL[t] = o;
        degL[t] = d > 32 ? 32 : d;
    }
    __syncthreads();
    // stage face lists; pad invalid slots with face 0 (hot line, select-zeroed)
#pragma unroll
    for (int r = 0; r < 4; ++r) {
        int i = t + r * 256;
        int row = i >> 5, j = i & 31;
        flatL[row][j] = (j < degL[row]) ? csr[offL[row] + j] : 0;
    }
    __syncthreads();

    // ---- gather: dual-row (qa, qb) per iteration -> 8 loads in flight.
    // deg is wave-uniform per row, so all selects/branches are uniform.
    for (int qq = 0; qq < 4; ++qq) {
        int qa = wid * 8 + qq;
        int qb = wid * 8 + 4 + qq;
        int na = degL[qa], nb = degL[qb];
        int jm = max(na, nb);
        float sa = 0.f, sb = 0.f;
        for (int j = 0; j < jm; j += 4) {
            int fa0 = flatL[qa][j + 0], fa1 = flatL[qa][j + 1];
            int fa2 = flatL[qa][j + 2], fa3 = flatL[qa][j + 3];
            int fb0 = flatL[qb][j + 0], fb1 = flatL[qb][j + 1];
            int fb2 = flatL[qb][j + 2], fb3 = flatL[qb][j + 3];
            float va0 = bf2f(ct[(size_t)fa0 * 64 + lane]);
            float va1 = bf2f(ct[(size_t)fa1 * 64 + lane]);
            float va2 = bf2f(ct[(size_t)fa2 * 64 + lane]);
            float va3 = bf2f(ct[(size_t)fa3 * 64 + lane]);
            float vb0 = bf2f(ct[(size_t)fb0 * 64 + lane]);
            float vb1 = bf2f(ct[(size_t)fb1 * 64 + lane]);
            float vb2 = bf2f(ct[(size_t)fb2 * 64 + lane]);
            float vb3 = bf2f(ct[(size_t)fb3 * 64 + lane]);
            sa += ((j + 0 < na) ? va0 : 0.f) + ((j + 1 < na) ? va1 : 0.f)
                + ((j + 2 < na) ? va2 : 0.f) + ((j + 3 < na) ? va3 : 0.f);
            sb += ((j + 0 < nb) ? vb0 : 0.f) + ((j + 1 < nb) ? vb1 : 0.f)
                + ((j + 2 < nb) ? vb2 : 0.f) + ((j + 3 < nb) ? vb3 : 0.f);
        }
        sa *= denL[qa];
        sb *= denL[qb];
        int swza = (lane & 7) | ((((lane >> 3) ^ (qa & 7))) << 3);
        int swzb = (lane & 7) | ((((lane >> 3) ^ (qb & 7))) << 3);
        A[qa * 64 + swza] = f2bf(sa);
        A[qb * 64 + swzb] = f2bf(sb);
    }
    __syncthreads();

    // ---- MFMA matmul: wave (mi, nb): mi = wid&1 (16 rows), nb = wid>>1
    const int mi = wid & 1;
    const int nbq = wid >> 1;
    f32x4 acc[4];
#pragma unroll
    for (int tt = 0; tt < 4; ++tt) acc[tt] = (f32x4){0.f, 0.f, 0.f, 0.f};
#pragma unroll
    for (int kk = 0; kk < 2; ++kk) {
        int row = mi * 16 + (lane & 15);
        int chunk = (kk * 4 + (lane >> 4)) ^ (row & 7);
        bf16x8 a = *(const bf16x8*)&A[row * 64 + chunk * 8];
#pragma unroll
        for (int tt = 0; tt < 4; ++tt) {
            int frag = (nbq * 4 + tt) * 2 + kk;
            bf16x8 b = *(const bf16x8*)&dwb[((size_t)frag * 64 + lane) * 8];
            acc[tt] = __builtin_amdgcn_mfma_f32_16x16x32_bf16(a, b, acc[tt], 0, 0, 0);
        }
    }

    // bias + ReLU + C-tile to LDS + BN stats
    float* st = stats + (blockIdx.x & 7) * 256;
#pragma unroll
    for (int tt = 0; tt < 4; ++tt) {
        int col = nbq * 64 + tt * 16 + (lane & 15);
        float bv = bias[col];
        float s = 0.f, s2 = 0.f;
#pragma unroll
        for (int i = 0; i < 4; ++i) {
            float o = fmaxf(acc[tt][i] + bv, 0.f);
            int row = mi * 16 + (lane >> 4) * 4 + i;
            outL[row * 128 + col] = f2bf(o);
            s  += o;
            s2 += o * o;
        }
        s  += __shfl_xor(s, 16);  s  += __shfl_xor(s, 32);
        s2 += __shfl_xor(s2, 16); s2 += __shfl_xor(s2, 32);
        if ((lane >> 4) == 0) {
            atomicAdd(&st[col], s);
            atomicAdd(&st[128 + col], s2);
        }
    }
    __syncthreads();

#pragma unroll
    for (int r = 0; r < 2; ++r) {
        int i = t + r * 256;
        ((int4*)&outb[(size_t)vbase * 128])[i] = ((const int4*)outL)[i];
    }
}

// ---- BatchNorm finalize: bf16 in (ws) -> f32 out (d_out) -----------------
__global__ __launch_bounds__(256) void bn_k(
    const __hip_bfloat16* __restrict__ outb,
    float* __restrict__ out,
    const float* __restrict__ stats,
    const float* __restrict__ gamma,
    const float* __restrict__ beta)
{
    __shared__ float sc[128], sh[128];
    if (threadIdx.x < 128) {
        int c = threadIdx.x;
        float s = 0.f, s2 = 0.f;
#pragma unroll
        for (int r = 0; r < 8; ++r) {
            s  += stats[r * 256 + c];
            s2 += stats[r * 256 + 128 + c];
        }
        float mean = s / (float)NVERT;
        float var  = s2 / (float)NVERT - mean * mean;
        float inv  = rsqrtf(var + BN_EPS) * gamma[c];
        sc[c] = inv;
        sh[c] = beta[c] - mean * inv;
    }
    __syncthreads();

    const unsigned short* ob = (const unsigned short*)outb;
    float4* o4 = (float4*)out;
    size_t total4 = (size_t)NVERT * COUT / 4;
    for (size_t i = (size_t)blockIdx.x * 256 + threadIdx.x; i < total4;
         i += (size_t)gridDim.x * 256) {
        int c0 = (int)((i * 4) & 127);
        ushort4 u = *(const ushort4*)&ob[i * 4];
        float4 v;
        v.x = bf2f(u.x) * sc[c0 + 0] + sh[c0 + 0];
        v.y = bf2f(u.y) * sc[c0 + 1] + sh[c0 + 1];
        v.z = bf2f(u.z) * sc[c0 + 2] + sh[c0 + 2];
        v.w = bf2f(u.w) * sc[c0 + 3] + sh[c0 + 3];
        o4[i] = v;
    }
}

extern "C" void kernel_launch(void* const* d_in, const int* in_sizes, int n_in,
                              void* d_out, int out_size, void* d_ws, size_t ws_size,
                              hipStream_t stream) {
    const float* inputs   = (const float*)d_in[0];
    const float* filt     = (const float*)d_in[1];
    const int*   face     = (const int*)d_in[2];
    const int*   nf_count = (const int*)d_in[3];
    const int*   vt_map   = (const int*)d_in[4];
    const float* sw       = (const float*)d_in[5];
    const float* dw       = (const float*)d_in[6];
    const float* bias     = (const float*)d_in[7];
    const float* gamma    = (const float*)d_in[8];
    const float* beta     = (const float*)d_in[9];
    float* out = (float*)d_out;

    // ws: [stats 8KB][swb 8KB][dwb 16KB][outb bf16 51.2MB]
    char* w = (char*)d_ws;
    float*          stats = (float*)w;
    short*          swb   = (short*)(w + 8192);
    short*          dwb   = (short*)(w + 16384);
    __hip_bfloat16* outb  = (__hip_bfloat16*)(w + 32768);

    // d_out staging (all dead before bn_k writes d_out):
    char* o = (char*)d_out;
    __hip_bfloat16* contrib      = (__hip_bfloat16*)o;
    int2*           pairs        = (int2*)(o + 51200000);
    int*            csr          = (int*)(o + 60800000);
    int*            row_off      = (int*)(o + 65600000);
    int*            blockcnt     = (int*)(o + 66400256);
    int*            bucket_start = (int*)(o + 66924544);
    const int*      faceflat     = face;

    hipMemsetAsync(stats, 0, 8192, stream);

    prep_k<<<1, 256, 0, stream>>>(sw, dw, swb, dwb);
    hist_k<<<NBLK, 256, 0, stream>>>(faceflat, blockcnt);
    scan_k<<<1, 256, 0, stream>>>(blockcnt, bucket_start, row_off);
    scat_k<<<NBLK, 256, 0, stream>>>(faceflat, blockcnt, pairs);
    csr_k<<<NB, 256, 0, stream>>>(pairs, bucket_start, row_off, csr);
    mix_k<<<NFACE / 64, 256, 0, stream>>>(inputs, filt, swb, contrib);
    pconv_k<<<NVERT / BV, 256, 0, stream>>>(contrib, row_off, csr, nf_count,
                                            vt_map, dwb, bias, outb, stats);
    bn_k<<<2048, 256, 0, stream>>>(outb, out, stats, gamma, beta);
}

// Round 15
// 188.535 us; speedup vs baseline: 1.3712x; 1.0083x over previous
//
#include <hip/hip_runtime.h>
#include <hip/hip_bf16.h>

#define NFACE 400000
#define NVERT 200000
#define CIN 64
#define COUT 128
#define KF 27
#define BN_EPS 1e-5f
#define LST 56            // Af row stride (shorts): 112B, bank-spread

#define M_TOT (NFACE * 3)            // 1.2M incidences
#define NB    391                    // coarse buckets: v>>9
#define NBLK  256                    // blocks for hist/scatter
#define CHUNK ((M_TOT + NBLK - 1) / NBLK)   // 4688

typedef __attribute__((ext_vector_type(8))) short bf16x8;
typedef __attribute__((ext_vector_type(4))) float f32x4;

__device__ __forceinline__ short f2bf(float x) {
    __hip_bfloat16 h = __float2bfloat16(x);
    return *reinterpret_cast<short*>(&h);
}
__device__ __forceinline__ float bf2f(unsigned short u) {
    union { unsigned int i; float f; } x; x.i = ((unsigned)u) << 16; return x.f;
}

// ---- prep: swf (mix B-frags) + dwb (pconv B-frags), both bf16 ------------
// swf[p*8+j], p=(cb*64+lane): element j of lane's B-fragment for col-block cb:
//   ch = cb*16 + (lane&15), k = (lane>>4)*8 + j  -> sw[k*64+ch] (0 if k>=27)
__global__ __launch_bounds__(256) void prep_k(const float* __restrict__ sw,
                                              const float* __restrict__ dw,
                                              short* __restrict__ swf,
                                              short* __restrict__ dwb) {
    int t = threadIdx.x;
    {
        int cb = t >> 6, lane = t & 63;
        int ch = cb * 16 + (lane & 15);
#pragma unroll
        for (int j = 0; j < 8; ++j) {
            int k = (lane >> 4) * 8 + j;
            swf[t * 8 + j] = (k < KF) ? f2bf(sw[k * 64 + ch]) : (short)0;
        }
    }
#pragma unroll
    for (int p4 = 0; p4 < 4; ++p4) {
        int p = t + p4 * 256;
        int frag = p >> 6, lane = p & 63;
        int nb = frag >> 3, tt = (frag >> 1) & 3, kk = frag & 1;
        int col = nb * 64 + tt * 16 + (lane & 15);
#pragma unroll
        for (int j = 0; j < 8; ++j) {
            int k = kk * 32 + (lane >> 4) * 8 + j;
            dwb[(size_t)p * 8 + j] = f2bf(dw[k * 128 + col]);
        }
    }
}

// ---- sort pass A: per-(block,bucket) histogram ---------------------------
__global__ __launch_bounds__(256) void hist_k(const int* __restrict__ faceflat,
                                              int* __restrict__ blockcnt) {
    __shared__ int h[512];
    const int t = threadIdx.x, blk = blockIdx.x;
    for (int j = t; j < 512; j += 256) h[j] = 0;
    __syncthreads();
    int e0 = blk * CHUNK;
    int e1 = min(e0 + CHUNK, M_TOT);
    for (int e = e0 + t; e < e1; e += 256)
        atomicAdd(&h[faceflat[e] >> 9], 1);
    __syncthreads();
    for (int j = t; j < 512; j += 256) blockcnt[blk * 512 + j] = h[j];
}

// ---- sort pass B: totals, exclusive scan, rebase per-block bases ---------
__global__ __launch_bounds__(256) void scan_k(int* __restrict__ blockcnt,
                                              int* __restrict__ bucket_start,
                                              int* __restrict__ row_off) {
    __shared__ int tot[512];
    __shared__ int bst[512];
    const int t = threadIdx.x;
    for (int b = t; b < 512; b += 256) {
        int acc = 0;
        if (b < NB)
            for (int k = 0; k < NBLK; ++k) acc += blockcnt[k * 512 + b];
        tot[b] = acc;
    }
    __syncthreads();
    if (t < 64) {
        int base8 = t * 8, loc[8], s = 0;
#pragma unroll
        for (int j = 0; j < 8; ++j) { loc[j] = s; s += tot[base8 + j]; }
        int v = s;
        for (int off = 1; off < 64; off <<= 1) {
            int u = __shfl_up(v, off);
            if (t >= off) v += u;
        }
        int excl = v - s;
#pragma unroll
        for (int j = 0; j < 8; ++j) bst[base8 + j] = excl + loc[j];
    }
    __syncthreads();
    for (int b = t; b < NB; b += 256) bucket_start[b] = bst[b];
    if (t == 0) { bucket_start[NB] = bst[NB]; row_off[NVERT] = M_TOT; }
    for (int b = t; b < NB; b += 256) {
        int acc = bst[b];
        for (int k = 0; k < NBLK; ++k) {
            int c = blockcnt[k * 512 + b];
            blockcnt[k * 512 + b] = acc;
            acc += c;
        }
    }
}

// ---- sort pass C: scatter pairs into bucket-major order ------------------
__global__ __launch_bounds__(256) void scat_k(const int* __restrict__ faceflat,
                                              const int* __restrict__ blockcnt,
                                              int2* __restrict__ pairs) {
    __shared__ int baseL[512];
    __shared__ int lc[512];
    const int t = threadIdx.x, blk = blockIdx.x;
    for (int j = t; j < 512; j += 256) { baseL[j] = blockcnt[blk * 512 + j]; lc[j] = 0; }
    __syncthreads();
    int e0 = blk * CHUNK;
    int e1 = min(e0 + CHUNK, M_TOT);
    for (int e = e0 + t; e < e1; e += 256) {
        int v = faceflat[e];
        int b = v >> 9;
        int l = atomicAdd(&lc[b], 1);
        pairs[baseL[b] + l] = make_int2(v, e / 3);
    }
}

// ---- sort pass D: per-bucket CSR build -----------------------------------
__global__ __launch_bounds__(256) void csr_k(const int2* __restrict__ pairs,
                                             const int* __restrict__ bucket_start,
                                             int* __restrict__ row_off,
                                             int* __restrict__ csr) {
    __shared__ int cnt[512], esc[512], pc[512];
    const int t = threadIdx.x, b = blockIdx.x;
    const int p0 = bucket_start[b], p1 = bucket_start[b + 1];
    const int vbase = b << 9;
    for (int j = t; j < 512; j += 256) { cnt[j] = 0; pc[j] = 0; }
    __syncthreads();
    for (int i = p0 + t; i < p1; i += 256)
        atomicAdd(&cnt[pairs[i].x - vbase], 1);
    __syncthreads();
    if (t < 64) {
        int base8 = t * 8, loc[8], s = 0;
#pragma unroll
        for (int j = 0; j < 8; ++j) { loc[j] = s; s += cnt[base8 + j]; }
        int v = s;
        for (int off = 1; off < 64; off <<= 1) {
            int u = __shfl_up(v, off);
            if (t >= off) v += u;
        }
        int excl = v - s;
#pragma unroll
        for (int j = 0; j < 8; ++j) esc[base8 + j] = excl + loc[j];
    }
    __syncthreads();
    int nvb = min(512, NVERT - vbase);
    for (int j = t; j < nvb; j += 256) row_off[vbase + j] = p0 + esc[j];
    for (int i = p0 + t; i < p1; i += 256) {
        int lv = pairs[i].x - vbase;
        int l = atomicAdd(&pc[lv], 1);
        csr[p0 + esc[lv] + l] = pairs[i].y;
    }
}

// ---- Kernel: MFMA spatial mix + coalesced elementwise --------------------
// B-fragments come prepacked from global (swf, L2/L3-broadcast) -> no Bs LDS.
__global__ __launch_bounds__(256) void mix_k(
    const float* __restrict__ inputs,   // [NF,64]
    const float* __restrict__ filt,     // [NF,27]
    const short* __restrict__ swf,      // [4*64][8] bf16 fragments
    __hip_bfloat16* __restrict__ contrib) // [NF,64]
{
    __shared__ __align__(16) char smem[16384];
    short* Af = (short*)smem;                 // 64*LST*2 = 7168 B
    float (*Wt)[64] = (float (*)[64])smem;    // phase 2 reuse: 16384 B

    const int t  = threadIdx.x;
    const int fb = blockIdx.x * 64;
    const int lane = t & 63;
    const int wid  = t >> 6;
    const int r0   = wid * 16;

    // B fragments: 4 coalesced 16B global loads (hot in L2)
    bf16x8 bfr[4];
#pragma unroll
    for (int cb = 0; cb < 4; ++cb)
        bfr[cb] = *(const bf16x8*)&swf[(cb * 64 + lane) * 8];

    // stage filt tile (coalesced 8B per thread per iter)
#pragma unroll
    for (int j = 0; j < 4; ++j) {
        int idx = t + j * 256;
        int fl = idx >> 4, k = (idx & 15) * 2;
        const float* fr = filt + (size_t)(fb + fl) * KF;
        float v0 = (k     < KF) ? fr[k]     : 0.f;
        float v1 = (k + 1 < KF) ? fr[k + 1] : 0.f;
        Af[fl * LST + k]     = f2bf(v0);
        Af[fl * LST + k + 1] = f2bf(v1);
    }
    __syncthreads();

    bf16x8 a = *(const bf16x8*)&Af[(r0 + (lane & 15)) * LST + (lane >> 4) * 8];
    f32x4 acc[4];
#pragma unroll
    for (int cb = 0; cb < 4; ++cb)
        acc[cb] = __builtin_amdgcn_mfma_f32_16x16x32_bf16(a, bfr[cb], (f32x4){0.f, 0.f, 0.f, 0.f}, 0, 0, 0);
    __syncthreads();   // all waves done reading Af before Wt overwrite

#pragma unroll
    for (int cb = 0; cb < 4; ++cb)
#pragma unroll
        for (int i = 0; i < 4; ++i)
            Wt[r0 + (lane >> 4) * 4 + i][cb * 16 + (lane & 15)] = acc[cb][i];
    __syncthreads();

#pragma unroll
    for (int p = 0; p < 4; ++p) {
        int idx = (p * 256 + t) * 4;
        int fl = idx >> 6, c = idx & 63;
        float4 in4 = *(const float4*)&inputs[(size_t)(fb + fl) * 64 + c];
        float4 w4  = *(const float4*)&Wt[fl][c];
        short4 o;
        o.x = f2bf(in4.x * w4.x);
        o.y = f2bf(in4.y * w4.y);
        o.z = f2bf(in4.z * w4.z);
        o.w = f2bf(in4.w * w4.w);
        *(short4*)((short*)contrib + (size_t)fb * 64 + idx) = o;
    }
}

// ---- pconv: CSR gather (quad-row, 16-deep MLP) + MFMA conv + stats -------
#define BV 32
__global__ __launch_bounds__(256, 6) void pconv_k(
    const __hip_bfloat16* __restrict__ contrib, // [NF,64]
    const int* __restrict__ row_off,            // [NV+1]
    const int* __restrict__ csr,                // [M]
    const int* __restrict__ nf_count,           // [NV]
    const int* __restrict__ vt_map,             // [NV] (int32)
    const short* __restrict__ dwb,              // prepped dw fragments
    const float* __restrict__ bias,             // [128]
    __hip_bfloat16* __restrict__ outb,          // [NV,128] bf16 (ws)
    float* __restrict__ stats)                  // [8][256]
{
    __shared__ float denL[BV];
    __shared__ int   offL[BV];
    __shared__ int   degL[BV];
    __shared__ int   flatL[BV][32];                // 4 KB (padded with face 0)
    __shared__ __align__(16) short A[BV * 64];     // swizzled bf16 A-tile, 4KB
    __shared__ __align__(16) short outL[BV * 128]; // C-tile bf16, 8KB

    const int t     = threadIdx.x;
    const int lane  = t & 63;
    const int wid   = t >> 6;
    const int vbase = blockIdx.x * BV;
    const unsigned short* ct = (const unsigned short*)contrib;

    if (t < BV) {
        int src = vt_map[vbase + t];
        denL[t] = 1.f / (float)max(nf_count[src], 1);
        int o = row_off[src];
        int d = row_off[src + 1] - o;
        offL[t] = o;
        degL[t] = d > 32 ? 32 : d;
    }
    __syncthreads();
    // stage face lists; pad invalid slots with face 0 (hot line, select-zeroed)
#pragma unroll
    for (int r = 0; r < 4; ++r) {
        int i = t + r * 256;
        int row = i >> 5, j = i & 31;
        flatL[row][j] = (j < degL[row]) ? csr[offL[row] + j] : 0;
    }
    __syncthreads();

    // ---- gather: quad-row per iteration -> 16 loads in flight.
    // deg is wave-uniform per row, so all selects are uniform.
#pragma unroll
    for (int g = 0; g < 2; ++g) {
        const int q0 = wid * 8 + g * 4;
        const int n0 = degL[q0 + 0], n1 = degL[q0 + 1];
        const int n2 = degL[q0 + 2], n3 = degL[q0 + 3];
        int jm = max(max(n0, n1), max(n2, n3));
        float s0 = 0.f, s1 = 0.f, s2 = 0.f, s3 = 0.f;
        for (int j = 0; j < jm; j += 4) {
            int f00 = flatL[q0 + 0][j + 0], f01 = flatL[q0 + 0][j + 1];
            int f02 = flatL[q0 + 0][j + 2], f03 = flatL[q0 + 0][j + 3];
            int f10 = flatL[q0 + 1][j + 0], f11 = flatL[q0 + 1][j + 1];
            int f12 = flatL[q0 + 1][j + 2], f13 = flatL[q0 + 1][j + 3];
            int f20 = flatL[q0 + 2][j + 0], f21 = flatL[q0 + 2][j + 1];
            int f22 = flatL[q0 + 2][j + 2], f23 = flatL[q0 + 2][j + 3];
            int f30 = flatL[q0 + 3][j + 0], f31 = flatL[q0 + 3][j + 1];
            int f32_ = flatL[q0 + 3][j + 2], f33 = flatL[q0 + 3][j + 3];
            float v00 = bf2f(ct[(size_t)f00 * 64 + lane]);
            float v01 = bf2f(ct[(size_t)f01 * 64 + lane]);
            float v02 = bf2f(ct[(size_t)f02 * 64 + lane]);
            float v03 = bf2f(ct[(size_t)f03 * 64 + lane]);
            float v10 = bf2f(ct[(size_t)f10 * 64 + lane]);
            float v11 = bf2f(ct[(size_t)f11 * 64 + lane]);
            float v12 = bf2f(ct[(size_t)f12 * 64 + lane]);
            float v13 = bf2f(ct[(size_t)f13 * 64 + lane]);
            float v20 = bf2f(ct[(size_t)f20 * 64 + lane]);
            float v21 = bf2f(ct[(size_t)f21 * 64 + lane]);
            float v22 = bf2f(ct[(size_t)f22 * 64 + lane]);
            float v23 = bf2f(ct[(size_t)f23 * 64 + lane]);
            float v30 = bf2f(ct[(size_t)f30 * 64 + lane]);
            float v31 = bf2f(ct[(size_t)f31 * 64 + lane]);
            float v32 = bf2f(ct[(size_t)f32_ * 64 + lane]);
            float v33 = bf2f(ct[(size_t)f33 * 64 + lane]);
            s0 += ((j + 0 < n0) ? v00 : 0.f) + ((j + 1 < n0) ? v01 : 0.f)
                + ((j + 2 < n0) ? v02 : 0.f) + ((j + 3 < n0) ? v03 : 0.f);
            s1 += ((j + 0 < n1) ? v10 : 0.f) + ((j + 1 < n1) ? v11 : 0.f)
                + ((j + 2 < n1) ? v12 : 0.f) + ((j + 3 < n1) ? v13 : 0.f);
            s2 += ((j + 0 < n2) ? v20 : 0.f) + ((j + 1 < n2) ? v21 : 0.f)
                + ((j + 2 < n2) ? v22 : 0.f) + ((j + 3 < n2) ? v23 : 0.f);
            s3 += ((j + 0 < n3) ? v30 : 0.f) + ((j + 1 < n3) ? v31 : 0.f)
                + ((j + 2 < n3) ? v32 : 0.f) + ((j + 3 < n3) ? v33 : 0.f);
        }
        s0 *= denL[q0 + 0]; s1 *= denL[q0 + 1];
        s2 *= denL[q0 + 2]; s3 *= denL[q0 + 3];
#pragma unroll
        for (int r = 0; r < 4; ++r) {
            int q = q0 + r;
            float sv = (r == 0) ? s0 : (r == 1) ? s1 : (r == 2) ? s2 : s3;
            int swz = (lane & 7) | ((((lane >> 3) ^ (q & 7))) << 3);
            A[q * 64 + swz] = f2bf(sv);
        }
    }
    __syncthreads();

    // ---- MFMA matmul: wave (mi, nbq): mi = wid&1 (16 rows), nbq = wid>>1
    const int mi = wid & 1;
    const int nbq = wid >> 1;
    f32x4 acc[4];
#pragma unroll
    for (int tt = 0; tt < 4; ++tt) acc[tt] = (f32x4){0.f, 0.f, 0.f, 0.f};
#pragma unroll
    for (int kk = 0; kk < 2; ++kk) {
        int row = mi * 16 + (lane & 15);
        int chunk = (kk * 4 + (lane >> 4)) ^ (row & 7);
        bf16x8 a = *(const bf16x8*)&A[row * 64 + chunk * 8];
#pragma unroll
        for (int tt = 0; tt < 4; ++tt) {
            int frag = (nbq * 4 + tt) * 2 + kk;
            bf16x8 b = *(const bf16x8*)&dwb[((size_t)frag * 64 + lane) * 8];
            acc[tt] = __builtin_amdgcn_mfma_f32_16x16x32_bf16(a, b, acc[tt], 0, 0, 0);
        }
    }

    // bias + ReLU + C-tile to LDS + BN stats
    float* st = stats + (blockIdx.x & 7) * 256;
#pragma unroll
    for (int tt = 0; tt < 4; ++tt) {
        int col = nbq * 64 + tt * 16 + (lane & 15);
        float bv = bias[col];
        float s = 0.f, s2 = 0.f;
#pragma unroll
        for (int i = 0; i < 4; ++i) {
            float o = fmaxf(acc[tt][i] + bv, 0.f);
            int row = mi * 16 + (lane >> 4) * 4 + i;
            outL[row * 128 + col] = f2bf(o);
            s  += o;
            s2 += o * o;
        }
        s  += __shfl_xor(s, 16);  s  += __shfl_xor(s, 32);
        s2 += __shfl_xor(s2, 16); s2 += __shfl_xor(s2, 32);
        if ((lane >> 4) == 0) {
            atomicAdd(&st[col], s);
            atomicAdd(&st[128 + col], s2);
        }
    }
    __syncthreads();

#pragma unroll
    for (int r = 0; r < 2; ++r) {
        int i = t + r * 256;
        ((int4*)&outb[(size_t)vbase * 128])[i] = ((const int4*)outL)[i];
    }
}

// ---- BatchNorm finalize: bf16 in (ws) -> f32 out (d_out) -----------------
__global__ __launch_bounds__(256) void bn_k(
    const __hip_bfloat16* __restrict__ outb,
    float* __restrict__ out,
    const float* __restrict__ stats,
    const float* __restrict__ gamma,
    const float* __restrict__ beta)
{
    __shared__ float sc[128], sh[128];
    if (threadIdx.x < 128) {
        int c = threadIdx.x;
        float s = 0.f, s2 = 0.f;
#pragma unroll
        for (int r = 0; r < 8; ++r) {
            s  += stats[r * 256 + c];
            s2 += stats[r * 256 + 128 + c];
        }
        float mean = s / (float)NVERT;
        float var  = s2 / (float)NVERT - mean * mean;
        float inv  = rsqrtf(var + BN_EPS) * gamma[c];
        sc[c] = inv;
        sh[c] = beta[c] - mean * inv;
    }
    __syncthreads();

    const unsigned short* ob = (const unsigned short*)outb;
    float4* o4 = (float4*)out;
    size_t total4 = (size_t)NVERT * COUT / 4;
    for (size_t i = (size_t)blockIdx.x * 256 + threadIdx.x; i < total4;
         i += (size_t)gridDim.x * 256) {
        int c0 = (int)((i * 4) & 127);
        ushort4 u = *(const ushort4*)&ob[i * 4];
        float4 v;
        v.x = bf2f(u.x) * sc[c0 + 0] + sh[c0 + 0];
        v.y = bf2f(u.y) * sc[c0 + 1] + sh[c0 + 1];
        v.z = bf2f(u.z) * sc[c0 + 2] + sh[c0 + 2];
        v.w = bf2f(u.w) * sc[c0 + 3] + sh[c0 + 3];
        o4[i] = v;
    }
}

extern "C" void kernel_launch(void* const* d_in, const int* in_sizes, int n_in,
                              void* d_out, int out_size, void* d_ws, size_t ws_size,
                              hipStream_t stream) {
    const float* inputs   = (const float*)d_in[0];
    const float* filt     = (const float*)d_in[1];
    const int*   face     = (const int*)d_in[2];
    const int*   nf_count = (const int*)d_in[3];
    const int*   vt_map   = (const int*)d_in[4];
    const float* sw       = (const float*)d_in[5];
    const float* dw       = (const float*)d_in[6];
    const float* bias     = (const float*)d_in[7];
    const float* gamma    = (const float*)d_in[8];
    const float* beta     = (const float*)d_in[9];
    float* out = (float*)d_out;

    // ws: [stats 8KB][swf 8KB][dwb 16KB][outb bf16 51.2MB]
    char* w = (char*)d_ws;
    float*          stats = (float*)w;
    short*          swf   = (short*)(w + 8192);
    short*          dwb   = (short*)(w + 16384);
    __hip_bfloat16* outb  = (__hip_bfloat16*)(w + 32768);

    // d_out staging (all dead before bn_k writes d_out):
    char* o = (char*)d_out;
    __hip_bfloat16* contrib      = (__hip_bfloat16*)o;
    int2*           pairs        = (int2*)(o + 51200000);
    int*            csr          = (int*)(o + 60800000);
    int*            row_off      = (int*)(o + 65600000);
    int*            blockcnt     = (int*)(o + 66400256);
    int*            bucket_start = (int*)(o + 66924544);
    const int*      faceflat     = face;

    hipMemsetAsync(stats, 0, 8192, stream);

    prep_k<<<1, 256, 0, stream>>>(sw, dw, swf, dwb);
    hist_k<<<NBLK, 256, 0, stream>>>(faceflat, blockcnt);
    scan_k<<<1, 256, 0, stream>>>(blockcnt, bucket_start, row_off);
    scat_k<<<NBLK, 256, 0, stream>>>(faceflat, blockcnt, pairs);
    csr_k<<<NB, 256, 0, stream>>>(pairs, bucket_start, row_off, csr);
    mix_k<<<NFACE / 64, 256, 0, stream>>>(inputs, filt, swf, contrib);
    pconv_k<<<NVERT / BV, 256, 0, stream>>>(contrib, row_off, csr, nf_count,
                                            vt_map, dwb, bias, outb, stats);
    bn_k<<<2048, 256, 0, stream>>>(outb, out, stats, gamma, beta);
}